// Round 4
// baseline (364.778 us; speedup 1.0000x reference)
//
#include <hip/hip_runtime.h>

// Chain of 9 Linear layers, no activation => collapse to one affine map.
// dims: 784 -> 69 -> 31 -> 10 -> ... -> 10
//
// R10: STREAMING REWRITE of the main kernel.
//   R9's counters exposed the truth: main loop ~100-125us reading 205MB of
//   x at only ~1.6-2 TB/s (streaming floor: 32.5us @ 6.3TB/s). VALU ~7us,
//   LDS ~20us -> latency/pattern-bound, not BW-bound. Every prior variant
//   read x as 8-12 scattered 128B segments at stride 3136B with depth-1
//   prefetch; pattern tweaks (64->12 lines/instr, 32->16 waves/CU) never
//   moved it. Fix: read x EXACTLY like the proven-6.3TB/s pattern (m13 /
//   harness fills): contiguous 1KB per wave instruction.
//     - block = 512 thr, 256 rows; block's span is CONTIGUOUS (row-major)
//     - 16 chunks x 16 rows (49KB), double-buffered LDS; reg-staged
//       (thread t loads float4 k*512+t: consecutive lanes = consecutive
//       addresses), issue-early/write-late, 1 barrier per chunk, ~50KB
//       in flight per CU under each chunk's compute
//     - compute from LDS: wave = 2 rows x 32 col-segs; weight reads
//       [200 j4][11 float4] layout: quad (3*c4+o)&7 spread, 2-way bcast,
//       ~4cyc/b128; x b128 at full LDS BW; LDS ~2700cyc/chunk/CU < HBM
//       budget 4900cyc
//     - 5-step shfl_xor reduce over the 32 lanes sharing a row; lanes
//       s<5 write float2
//   LDS 132KB -> 1 block/CU; grid 256 = 1 block/CU, latency hidden by
//   in-flight bytes (not TLP), m13-style.
//
// prep_all (R7/R8, proven): 18 blocks x 512; every block redundantly
//   computes the collapse chain S8 = W8*...*W1 in its own LDS, folds its
//   512-entry slice of Wt2 from LOCAL LDS; block 0 emits beff.
//
// Wt2 layout: [200 j-quads][11 float4]; entry (j4, o<10) = {W[o][j4*4+k]};
// o==10 and j4 in [196,200) are zero padding.

__global__ void prep_all(
    const float* __restrict__ W0,
    const float* __restrict__ W1, const float* __restrict__ b1,
    const float* __restrict__ W2, const float* __restrict__ b2,
    const float* __restrict__ W3, const float* __restrict__ b3,
    const float* __restrict__ W4, const float* __restrict__ b4,
    const float* __restrict__ W5, const float* __restrict__ b5,
    const float* __restrict__ W6, const float* __restrict__ b6,
    const float* __restrict__ W7, const float* __restrict__ b7,
    const float* __restrict__ W8, const float* __restrict__ b8,
    const float* __restrict__ b0,
    float* __restrict__ Wt2, float* __restrict__ beff)
{
    __shared__ float Sa[31 * 69], Sb[31 * 69];
    __shared__ float da[31], db[31];
    const int t = threadIdx.x;
    const int nt = blockDim.x;

    for (int i = t; i < 31 * 69; i += nt) Sa[i] = W1[i];
    for (int i = t; i < 31; i += nt) da[i] = b1[i];
    __syncthreads();

    for (int i = t; i < 10 * 69; i += nt) {
        int o = i / 69, c = i - o * 69;
        float s = 0.f;
        for (int k = 0; k < 31; k++) s += W2[o * 31 + k] * Sa[k * 69 + c];
        Sb[i] = s;
    }
    for (int i = t; i < 10; i += nt) {
        float s = b2[i];
        for (int k = 0; k < 31; k++) s += W2[i * 31 + k] * da[k];
        db[i] = s;
    }
    __syncthreads();

    const float* Wk[6] = { W3, W4, W5, W6, W7, W8 };
    const float* bk[6] = { b3, b4, b5, b6, b7, b8 };
    int src = 1;  // runtime ternaries: gfx950 rejects arrays of LDS pointers
    for (int st = 0; st < 6; st++) {
        const float* W = Wk[st];
        const float* bb = bk[st];
        float* S  = src ? Sb : Sa;
        float* D  = src ? Sa : Sb;
        float* dd = src ? db : da;
        float* dn = src ? da : db;
        for (int i = t; i < 10 * 69; i += nt) {
            int o = i / 69, c = i - o * 69;
            float s = 0.f;
            for (int k = 0; k < 10; k++) s += W[o * 10 + k] * S[k * 69 + c];
            D[i] = s;
        }
        for (int i = t; i < 10; i += nt) {
            float s = bb[i];
            for (int k = 0; k < 10; k++) s += W[i * 10 + k] * dd[k];
            dn[i] = s;
        }
        __syncthreads();
        src ^= 1;
    }

    float* S  = src ? Sb : Sa;   // src back to 1 after 6 flips -> Sb
    float* dd = src ? db : da;

    if (blockIdx.x == 0) {
        for (int i = t; i < 10; i += nt) {
            float s = dd[i];
            for (int k = 0; k < 69; k++) s += S[i * 69 + k] * b0[k];
            beff[i] = s;
        }
    }

    int e = blockIdx.x * nt + t;   // 0..9215, need 0..8799
    if (e < 8800) {
        int j4 = e / 44, rem = e - j4 * 44;
        float val = 0.f;
        if (rem < 40) {
            int o = rem >> 2, k = rem & 3, j = j4 * 4 + k;
            if (j < 784) {
                for (int u = 0; u < 69; u++) val += S[o * 69 + u] * W0[u * 784 + j];
            }
        }
        Wt2[e] = val;
    }
}

// ---- main (R10: contiguous-streaming x through LDS) ----

__global__ __launch_bounds__(512, 2) void linear_stream(
    const float* __restrict__ x, const float* __restrict__ Wt2,
    const float* __restrict__ beff, float* __restrict__ out)
{
    __shared__ float4 wlds[2200];     // 35.2 KB folded weights
    __shared__ float4 xb[2][3136];    // 2 x 49 KB x chunks (16 rows each)

    const int t = threadIdx.x;
    const int w = t >> 6;             // wave 0..7
    const int r = (t >> 5) & 1;       // row within wave's pair
    const int s = t & 31;             // col segment (4 floats each)
    const long blk_f4 = (long)blockIdx.x * 50176;   // 256 rows * 196 f4
    const float4* xg = (const float4*)x;

    // stage weights (L2-hot; overlaps chunk-0 x loads)
    {
        const float4* wg = (const float4*)Wt2;
        for (int i = t; i < 2200; i += 512) wlds[i] = wg[i];
    }

    float beL = 0.f, beH = 0.f;
    if (s < 5) { beL = beff[2 * s]; beH = beff[2 * s + 1]; }

    // prologue: stage chunk 0 (contiguous: lane-consecutive float4s)
    float4 xgr[7];
#pragma unroll
    for (int k = 0; k < 6; k++) xgr[k] = xg[blk_f4 + k * 512 + t];
    if (t < 64) xgr[6] = xg[blk_f4 + 3072 + t];      // wave 0 only: no divergence
#pragma unroll
    for (int k = 0; k < 6; k++) xb[0][k * 512 + t] = xgr[k];
    if (t < 64) xb[0][3072 + t] = xgr[6];
    __syncthreads();

    for (int c = 0; c < 16; c++) {
        // issue next chunk's global loads NOW (consumed after compute)
        if (c < 15) {
            const long base = blk_f4 + (long)(c + 1) * 3136;
#pragma unroll
            for (int k = 0; k < 6; k++) xgr[k] = xg[base + k * 512 + t];
            if (t < 64) xgr[6] = xg[base + 3072 + t];
        }

        // compute chunk c from LDS; wave w owns rows 2w, 2w+1 of the chunk
        const float4* xrow = &xb[c & 1][(2 * w + r) * 196];
        float acc[10];
#pragma unroll
        for (int o = 0; o < 10; o++) acc[o] = 0.f;

#pragma unroll
        for (int it = 0; it < 6; it++) {
            float4 xc = xrow[it * 32 + s];
            const float4* wr = &wlds[(it * 32 + s) * 11];
#pragma unroll
            for (int o = 0; o < 10; o++) {
                float4 wv = wr[o];
                acc[o] = fmaf(xc.x, wv.x, acc[o]);
                acc[o] = fmaf(xc.y, wv.y, acc[o]);
                acc[o] = fmaf(xc.z, wv.z, acc[o]);
                acc[o] = fmaf(xc.w, wv.w, acc[o]);
            }
        }
        if (s < 4) {                  // tail: cols 768..783 (c4 = 192+s)
            float4 xc = xrow[192 + s];
            const float4* wr = &wlds[(192 + s) * 11];
#pragma unroll
            for (int o = 0; o < 10; o++) {
                float4 wv = wr[o];
                acc[o] = fmaf(xc.x, wv.x, acc[o]);
                acc[o] = fmaf(xc.y, wv.y, acc[o]);
                acc[o] = fmaf(xc.z, wv.z, acc[o]);
                acc[o] = fmaf(xc.w, wv.w, acc[o]);
            }
        }

        // butterfly sum over the 32 lanes sharing this row (bits 0..4)
#pragma unroll
        for (int m = 1; m < 32; m <<= 1)
#pragma unroll
            for (int o = 0; o < 10; o++) acc[o] += __shfl_xor(acc[o], m, 64);

        // lanes s<5 write float2 (out + row*10 is 8B-aligned)
        {
            const long row = (long)blockIdx.x * 256 + c * 16 + 2 * w + r;
            if (s < 5) {
                float lo = 0.f, hi = 0.f;
#pragma unroll
                for (int o = 0; o < 5; o++) {
                    if (s == o) { lo = acc[2 * o]; hi = acc[2 * o + 1]; }  // cndmask chain
                }
                *(float2*)(out + row * 10 + s * 2) = make_float2(lo + beL, hi + beH);
            }
        }

        // write next chunk into the other buffer (disjoint from reads above)
        if (c < 15) {
            float4* dst = xb[(c + 1) & 1];
#pragma unroll
            for (int k = 0; k < 6; k++) dst[k * 512 + t] = xgr[k];
            if (t < 64) dst[3072 + t] = xgr[6];
            __syncthreads();          // writes visible before compute(c+1)
        }
    }
}

extern "C" void kernel_launch(void* const* d_in, const int* in_sizes, int n_in,
                              void* d_out, int out_size, void* d_ws, size_t ws_size,
                              hipStream_t stream) {
    const float* x  = (const float*)d_in[0];
    const float* W0 = (const float*)d_in[1];
    const float* b0 = (const float*)d_in[2];
    const float* W1 = (const float*)d_in[3];
    const float* b1 = (const float*)d_in[4];
    const float* W2 = (const float*)d_in[5];
    const float* b2 = (const float*)d_in[6];
    const float* W3 = (const float*)d_in[7];
    const float* b3 = (const float*)d_in[8];
    const float* W4 = (const float*)d_in[9];
    const float* b4 = (const float*)d_in[10];
    const float* W5 = (const float*)d_in[11];
    const float* b5 = (const float*)d_in[12];
    const float* W6 = (const float*)d_in[13];
    const float* b6 = (const float*)d_in[14];
    const float* W7 = (const float*)d_in[15];
    const float* b7 = (const float*)d_in[16];
    const float* W8 = (const float*)d_in[17];
    const float* b8 = (const float*)d_in[18];

    float* ws   = (float*)d_ws;
    float* Wt2  = ws;            // 8800 floats: [200 j4][11 float4]
    float* beff = ws + 8800;     // 10 floats

    float* out = (float*)d_out;
    const int B = in_sizes[0] / 784;  // 65536

    prep_all<<<18, 512, 0, stream>>>(W0, W1, b1, W2, b2, W3, b3, W4, b4,
                                     W5, b5, W6, b6, W7, b7, W8, b8,
                                     b0, Wt2, beff);
    linear_stream<<<B / 256, 512, 0, stream>>>(x, Wt2, beff, out);
}

// Round 5
// 318.322 us; speedup vs baseline: 1.1459x; 1.1459x over previous
//
#include <hip/hip_runtime.h>

// Chain of 9 Linear layers, no activation => collapse to one affine map.
// dims: 784 -> 69 -> 31 -> 10 -> ... -> 10
//
// R11: NON-TEMPORAL x loads + depth-2 prefetch on the R8 main structure.
//   Ledger: R8 scattered-lines ~99us, R9 fused ~126us, R10 contiguous
//   ~128us -> x-delivery stuck at 1.6-2 TB/s REGARDLESS of pattern, all
//   pipes idle (R9: VALU 20%, HBM 10%, occ 50%). R9 FETCH_SIZE ~106MB of
//   a 205MB read: half the stream is L3-warm (x fits in 256MB Infinity
//   Cache). Every proven 6.3-6.7 TB/s pattern on this chip (m13 copy,
//   harness fills) is L3-cold/streaming. Theory: the L3-warm scattered-
//   read service path is the ~2TB/s ceiling. Fix: __builtin_nontemporal_
//   load on x (global_load_dwordx4 nt -> pure-HBM streaming class, no L3
//   allocation) + depth-2 software pipeline (4KB/wave in flight, vmcnt>0
//   across the body) for HBM-latency tolerance.
//   FP order, lane->j ownership, butterfly, writes: byte-identical to R8
//   -> absmax must stay 0.0009765625.
//
// MAIN (R8 base): 2 rows/lane. s = t&7 owns j = jb*32+s*4; rows (t>>3),
//   +64. x loads coalesced (8 rows x 128B whole lines per instr, x2 row
//   sets). Weights in LDS, padded 11*float4 per j-quad: start bank quad
//   (3s+o)&7 -> all 8 addr groups disjoint, 8-way broadcast: conflict-
//   free. Tail 784=24*32+16: weight j4 196..199 zeroed, x addr clamped
//   to 780 (clamped elements hit zero weights). LDS 35.2KB -> 2 blocks/
//   CU (grid 512), 16 waves/CU.
//
// prep_all (R7, proven): 18 blocks x 512; every block redundantly
//   computes the collapse chain S8 = W8*...*W1 in its own LDS, folds its
//   512-entry slice of Wt2 from LOCAL LDS; block 0 emits beff.
//
// Wt2 layout: [200 j-quads][11 float4]; entry (j4, o<10) = {W[o][j4*4+k]};
// o==10 and j4 in [196,200) are zero padding.

typedef float vf4 __attribute__((ext_vector_type(4)));

__device__ __forceinline__ vf4 ntld(const float* p) {
    return __builtin_nontemporal_load((const vf4*)p);
}

__global__ void prep_all(
    const float* __restrict__ W0,
    const float* __restrict__ W1, const float* __restrict__ b1,
    const float* __restrict__ W2, const float* __restrict__ b2,
    const float* __restrict__ W3, const float* __restrict__ b3,
    const float* __restrict__ W4, const float* __restrict__ b4,
    const float* __restrict__ W5, const float* __restrict__ b5,
    const float* __restrict__ W6, const float* __restrict__ b6,
    const float* __restrict__ W7, const float* __restrict__ b7,
    const float* __restrict__ W8, const float* __restrict__ b8,
    const float* __restrict__ b0,
    float* __restrict__ Wt2, float* __restrict__ beff)
{
    __shared__ float Sa[31 * 69], Sb[31 * 69];
    __shared__ float da[31], db[31];
    const int t = threadIdx.x;
    const int nt = blockDim.x;

    for (int i = t; i < 31 * 69; i += nt) Sa[i] = W1[i];
    for (int i = t; i < 31; i += nt) da[i] = b1[i];
    __syncthreads();

    for (int i = t; i < 10 * 69; i += nt) {
        int o = i / 69, c = i - o * 69;
        float s = 0.f;
        for (int k = 0; k < 31; k++) s += W2[o * 31 + k] * Sa[k * 69 + c];
        Sb[i] = s;
    }
    for (int i = t; i < 10; i += nt) {
        float s = b2[i];
        for (int k = 0; k < 31; k++) s += W2[i * 31 + k] * da[k];
        db[i] = s;
    }
    __syncthreads();

    const float* Wk[6] = { W3, W4, W5, W6, W7, W8 };
    const float* bk[6] = { b3, b4, b5, b6, b7, b8 };
    int src = 1;  // runtime ternaries: gfx950 rejects arrays of LDS pointers
    for (int st = 0; st < 6; st++) {
        const float* W = Wk[st];
        const float* bb = bk[st];
        float* S  = src ? Sb : Sa;
        float* D  = src ? Sa : Sb;
        float* dd = src ? db : da;
        float* dn = src ? da : db;
        for (int i = t; i < 10 * 69; i += nt) {
            int o = i / 69, c = i - o * 69;
            float s = 0.f;
            for (int k = 0; k < 10; k++) s += W[o * 10 + k] * S[k * 69 + c];
            D[i] = s;
        }
        for (int i = t; i < 10; i += nt) {
            float s = bb[i];
            for (int k = 0; k < 10; k++) s += W[i * 10 + k] * dd[k];
            dn[i] = s;
        }
        __syncthreads();
        src ^= 1;
    }

    float* S  = src ? Sb : Sa;   // src back to 1 after 6 flips -> Sb
    float* dd = src ? db : da;

    if (blockIdx.x == 0) {
        for (int i = t; i < 10; i += nt) {
            float s = dd[i];
            for (int k = 0; k < 69; k++) s += S[i * 69 + k] * b0[k];
            beff[i] = s;
        }
    }

    int e = blockIdx.x * nt + t;   // 0..9215, need 0..8799
    if (e < 8800) {
        int j4 = e / 44, rem = e - j4 * 44;
        float val = 0.f;
        if (rem < 40) {
            int o = rem >> 2, k = rem & 3, j = j4 * 4 + k;
            if (j < 784) {
                for (int u = 0; u < 69; u++) val += S[o * 69 + u] * W0[u * 784 + j];
            }
        }
        Wt2[e] = val;
    }
}

// ---- main (R11: R8 + nt loads + depth-2 prefetch) ----

__global__ __launch_bounds__(512, 4) void linear_main(
    const float* __restrict__ x, const float* __restrict__ Wt2,
    const float* __restrict__ beff, float* __restrict__ out)
{
    __shared__ float4 wlds[2200];   // 35.2 KB
    const int t = threadIdx.x;
    const int s = t & 7;                         // j-segment within row group
    const long row0 = (long)blockIdx.x * 128 + (t >> 3);   // second row = row0+64
    const float* xr0 = x + row0 * 784;
    const float* xr1 = xr0 + (long)64 * 784;
    const int j0 = s * 4;

    // stage weights (independent of the x loads)
    {
        const float4* wg = (const float4*)Wt2;
        for (int i = t; i < 2200; i += 512) wlds[i] = wg[i];
    }

    float acc0[10], acc1[10];
#pragma unroll
    for (int o = 0; o < 10; o++) { acc0[o] = 0.f; acc1[o] = 0.f; }

    // depth-2 prefetch issued before the barrier (nt: bypass/no-alloc caches)
#define JADDR(JB) ((JB) * 32 + j0 > 780 ? 780 : (JB) * 32 + j0)
    vf4 a0 = ntld(xr0 + j0),  a1 = ntld(xr1 + j0);        // jb=0
    vf4 b0 = ntld(xr0 + 32 + j0), b1 = ntld(xr1 + 32 + j0); // jb=1
    __syncthreads();

#define BODY(XC0, XC1, JB) { \
    const float4* wrow = &wlds[((JB) * 8 + s) * 11]; \
    _Pragma("unroll") \
    for (int o = 0; o < 10; o++) { \
        float4 wv = wrow[o]; \
        acc0[o] = fmaf((XC0).x, wv.x, acc0[o]); \
        acc0[o] = fmaf((XC0).y, wv.y, acc0[o]); \
        acc0[o] = fmaf((XC0).z, wv.z, acc0[o]); \
        acc0[o] = fmaf((XC0).w, wv.w, acc0[o]); \
        acc1[o] = fmaf((XC1).x, wv.x, acc1[o]); \
        acc1[o] = fmaf((XC1).y, wv.y, acc1[o]); \
        acc1[o] = fmaf((XC1).z, wv.z, acc1[o]); \
        acc1[o] = fmaf((XC1).w, wv.w, acc1[o]); \
    } }

    for (int jb = 0; jb < 24; jb += 2) {
        // A body: consume a*, refill for jb+2 (clamped addr: tail weights = 0)
        vf4 c0 = a0, c1 = a1;
        a0 = ntld(xr0 + JADDR(jb + 2));
        a1 = ntld(xr1 + JADDR(jb + 2));
        BODY(c0, c1, jb);
        // B body: consume b*, refill for jb+3
        vf4 d0 = b0, d1 = b1;
        b0 = ntld(xr0 + JADDR(jb + 3));
        b1 = ntld(xr1 + JADDR(jb + 3));
        BODY(d0, d1, jb + 1);
    }
    BODY(a0, a1, 24);   // a* holds JADDR(24), loaded at jb=22

#undef BODY
#undef JADDR

    // butterfly sum over the 8 lanes sharing each row (bits 0..2 of lane id)
#pragma unroll
    for (int m = 1; m < 8; m <<= 1)
#pragma unroll
        for (int o = 0; o < 10; o++) {
            acc0[o] += __shfl_xor(acc0[o], m, 64);
            acc1[o] += __shfl_xor(acc1[o], m, 64);
        }

    // lanes s<5 write float2 per row (out + row*10 is 8B-aligned; 40B per row)
    if (s < 5) {
        float lo0 = 0.f, hi0 = 0.f, lo1 = 0.f, hi1 = 0.f;
#pragma unroll
        for (int o = 0; o < 5; o++) {
            if (s == o) {                         // cndmask chain
                lo0 = acc0[2 * o]; hi0 = acc0[2 * o + 1];
                lo1 = acc1[2 * o]; hi1 = acc1[2 * o + 1];
            }
        }
        float be0 = beff[s * 2], be1 = beff[s * 2 + 1];
        *(float2*)(out + row0 * 10 + s * 2) = make_float2(lo0 + be0, hi0 + be1);
        *(float2*)(out + (row0 + 64) * 10 + s * 2) = make_float2(lo1 + be0, hi1 + be1);
    }
}

extern "C" void kernel_launch(void* const* d_in, const int* in_sizes, int n_in,
                              void* d_out, int out_size, void* d_ws, size_t ws_size,
                              hipStream_t stream) {
    const float* x  = (const float*)d_in[0];
    const float* W0 = (const float*)d_in[1];
    const float* b0 = (const float*)d_in[2];
    const float* W1 = (const float*)d_in[3];
    const float* b1 = (const float*)d_in[4];
    const float* W2 = (const float*)d_in[5];
    const float* b2 = (const float*)d_in[6];
    const float* W3 = (const float*)d_in[7];
    const float* b3 = (const float*)d_in[8];
    const float* W4 = (const float*)d_in[9];
    const float* b4 = (const float*)d_in[10];
    const float* W5 = (const float*)d_in[11];
    const float* b5 = (const float*)d_in[12];
    const float* W6 = (const float*)d_in[13];
    const float* b6 = (const float*)d_in[14];
    const float* W7 = (const float*)d_in[15];
    const float* b7 = (const float*)d_in[16];
    const float* W8 = (const float*)d_in[17];
    const float* b8 = (const float*)d_in[18];

    float* ws   = (float*)d_ws;
    float* Wt2  = ws;            // 8800 floats: [200 j4][11 float4]
    float* beff = ws + 8800;     // 10 floats

    float* out = (float*)d_out;
    const int B = in_sizes[0] / 784;  // 65536

    prep_all<<<18, 512, 0, stream>>>(W0, W1, b1, W2, b2, W3, b3, W4, b4,
                                     W5, b5, W6, b6, W7, b7, W8, b8,
                                     b0, Wt2, beff);
    linear_main<<<B / 128, 512, 0, stream>>>(x, Wt2, beff, out);
}